// Round 10
// baseline (161.434 us; speedup 1.0000x reference)
//
#include <hip/hip_runtime.h>
#include <math.h>

#define B_   32
#define S_   512
#define D_   768
#define C_   128   // MAX_CHUNK_NUMBER
#define LCK  8     // MAX_CHUNK_LEN

#define MT     32                 // rows per logits tile
#define NTILE  12                 // tiles per batch (Tb <= 381)
#define NKS    24                 // 32-wide k-steps
#define P1_UNITS (B_ * NTILE)     // 384 blocks: (b, tile), full e-range per block

typedef _Float16 half8_t __attribute__((ext_vector_type(8)));
typedef float    f32x4   __attribute__((ext_vector_type(4)));

struct Args {
    const float* X; const int* lens; const float* W;
    const float* db; const float* ab; const float* q;
    const float* lnw; const float* lnb;
    float* cf; float* sent;
    int* starts; int* Tb; float* Lc;
    _Float16* Wt;      // [48 etile][24 ks][64 lane][8] = 1.125 MB, frag-contiguous
    float* partial;    // [32 b][512 t]
    float* pmax;       // [32 b][8 g][768 d] partial maxima
};

__device__ __forceinline__ float fast_tanh(float x) {
    float e = __expf(2.0f * x);
    return 1.0f - 2.0f / (e + 1.0f);   // exact saturation at +/-inf
}

// ---------------- k_prep: Wt transpose | per-batch scan | Lc ----------------
// bid 0..287   : Wt[et][ks][lane][j] = (fp16) W[et*16+(lane&15)][ks*32+(lane>>4)*8+j]
// bid 288..319 : exclusive scan of chunk_lens for batch bid-288
// bid 320      : Lc = sum_e q[e]*tanh(db[e]+ab[e])
__global__ __launch_bounds__(256) void k_prep(Args a) {
    const int tid = threadIdx.x, bid = blockIdx.x;
    if (bid < 288) {
        int u    = bid * 256 + tid;        // 0..73727 frag-words
        int lane = u & 63;
        int ks   = (u >> 6) % NKS;
        int et   = u / (64 * NKS);
        int e    = et * 16 + (lane & 15);
        int k    = ks * 32 + ((lane >> 4) << 3);
        const float* src = a.W + (size_t)e * D_ + k;
        float4 f0 = *(const float4*)src;
        float4 f1 = *(const float4*)(src + 4);
        half8_t h;
        h[0] = (_Float16)f0.x; h[1] = (_Float16)f0.y;
        h[2] = (_Float16)f0.z; h[3] = (_Float16)f0.w;
        h[4] = (_Float16)f1.x; h[5] = (_Float16)f1.y;
        h[6] = (_Float16)f1.z; h[7] = (_Float16)f1.w;
        *(half8_t*)(a.Wt + (size_t)u * 8) = h;    // coalesced write
    } else if (bid < 320) {
        int b = bid - 288;
        __shared__ int s_scan[256];
        int v = (tid < C_) ? a.lens[b * C_ + tid] : 0;
        s_scan[tid] = v;
        __syncthreads();
        #pragma unroll
        for (int off = 1; off < C_; off <<= 1) {
            int add = (tid >= off) ? s_scan[tid - off] : 0;
            __syncthreads();
            s_scan[tid] += add;
            __syncthreads();
        }
        if (tid < C_) {
            a.starts[b * C_ + tid] = s_scan[tid] - v;
            if (tid == C_ - 1) a.Tb[b] = s_scan[C_ - 1];
        }
    } else {
        __shared__ float s_lcred[256];
        float p = 0.f;
        for (int e = tid; e < D_; e += 256) p += fast_tanh(a.db[e] + a.ab[e]) * a.q[e];
        s_lcred[tid] = p;
        __syncthreads();
        for (int off = 128; off > 0; off >>= 1) {
            if (tid < off) s_lcred[tid] += s_lcred[tid + off];
            __syncthreads();
        }
        if (tid == 0) *a.Lc = s_lcred[0];
    }
}

// ---------------- k_logits ----------------
// logit[b,t] = sum_e q[e]*tanh( sum_d X[b,t,d]*W[e,d] + db[e]+ab[e] )
// Unit = (b, 32-row tile), FULL e-range (X read once). X staged to 48 KB LDS
// (fp16, XOR-swizzled). K-loop: 2 ds_read A-frags + 12 coalesced 1-KB Wt
// frag-loads (L2-resident) + 24 MFMA -> acc[2][12].
// A-frag (16x16x32 f16): lane holds A[m0+mt*16+(l&15)][ks*32+(l>>4)*8+j]
// B-frag: lane holds W[e][same k], e = etile*16+(l&15), etile = wid*12+nt
// C/D: col=lane&15 (e), row=(lane>>4)*4+r (m)   [validated rounds 3-9]
__global__ __launch_bounds__(256) void k_logits(Args a) {
    __shared__ _Float16 Xs[MT * D_];   // 48 KB
    __shared__ float s_red[4][32];
    const int tid = threadIdx.x, lane = tid & 63, wid = tid >> 6;
    const int erow = lane & 15;
    const int krow = (lane >> 4) * 8;

    int u    = blockIdx.x;
    int b    = u / NTILE;
    int tile = u % NTILE;
    int m0   = tile * MT;
    if (m0 >= a.Tb[b]) return;   // block-uniform

    // ---- stage X tile (32 rows x 768 k) fp32 -> fp16 LDS, swizzled ----
    {
        const float* Xb = a.X + ((size_t)(b * S_ + m0)) * D_;
        #pragma unroll
        for (int it = 0; it < 12; ++it) {
            int idx = it * 256 + tid;        // 0..3071 half8 units
            int row = idx / 96;
            int kk8 = idx % 96;
            const float* src = Xb + (size_t)row * D_ + kk8 * 8;
            float4 f0 = *(const float4*)src;
            float4 f1 = *(const float4*)(src + 4);
            half8_t h;
            h[0] = (_Float16)f0.x; h[1] = (_Float16)f0.y;
            h[2] = (_Float16)f0.z; h[3] = (_Float16)f0.w;
            h[4] = (_Float16)f1.x; h[5] = (_Float16)f1.y;
            h[6] = (_Float16)f1.z; h[7] = (_Float16)f1.w;
            int byte = row * 1536 + kk8 * 16;
            byte ^= (row & 7) << 4;
            *(half8_t*)((char*)Xs + byte) = h;
        }
    }
    __syncthreads();

    // ---- K loop: 12 coalesced Wt frag loads + 24 MFMA per ks ----
    const int et0 = wid * 12;   // this wave: 12 e-tiles = 192 cols
    const _Float16* Wb = a.Wt + (((size_t)et0 * NKS) * 64 + lane) * 8;
    f32x4 acc[2][12];
    #pragma unroll
    for (int mt = 0; mt < 2; ++mt)
        #pragma unroll
        for (int nt = 0; nt < 12; ++nt) acc[mt][nt] = (f32x4)(0.f);

    #pragma unroll 2
    for (int ks = 0; ks < NKS; ++ks) {
        half8_t av[2];
        #pragma unroll
        for (int mt = 0; mt < 2; ++mt) {
            int row  = mt * 16 + erow;
            int byte = row * 1536 + (ks * 32 + krow) * 2;
            byte ^= (row & 7) << 4;
            av[mt] = *(const half8_t*)((const char*)Xs + byte);
        }
        #pragma unroll
        for (int nt = 0; nt < 12; ++nt) {
            half8_t bv = *(const half8_t*)(Wb + ((size_t)nt * NKS + ks) * 64 * 8);
            acc[0][nt] = __builtin_amdgcn_mfma_f32_16x16x32_f16(av[0], bv, acc[0][nt], 0, 0, 0);
            acc[1][nt] = __builtin_amdgcn_mfma_f32_16x16x32_f16(av[1], bv, acc[1][nt], 0, 0, 0);
        }
    }

    // ---- epilogue: tanh + q-dot ----
    float lsum[2][4] = {{0.f,0.f,0.f,0.f},{0.f,0.f,0.f,0.f}};
    #pragma unroll
    for (int nt = 0; nt < 12; ++nt) {
        int e = (et0 + nt) * 16 + erow;
        float beta = a.db[e] + a.ab[e];
        float qe = a.q[e];
        #pragma unroll
        for (int r = 0; r < 4; ++r) {
            lsum[0][r] += fast_tanh(acc[0][nt][r] + beta) * qe;
            lsum[1][r] += fast_tanh(acc[1][nt][r] + beta) * qe;
        }
    }
    #pragma unroll
    for (int off = 1; off < 16; off <<= 1)
        #pragma unroll
        for (int mt = 0; mt < 2; ++mt)
            #pragma unroll
            for (int r = 0; r < 4; ++r)
                lsum[mt][r] += __shfl_xor(lsum[mt][r], off, 64);

    __syncthreads();
    if (erow == 0) {
        #pragma unroll
        for (int mt = 0; mt < 2; ++mt)
            #pragma unroll
            for (int r = 0; r < 4; ++r)
                s_red[wid][mt * 16 + (lane >> 4) * 4 + r] = lsum[mt][r];
    }
    __syncthreads();
    if (tid < MT)
        a.partial[(size_t)b * S_ + m0 + tid] =
            s_red[0][tid] + s_red[1][tid] + s_red[2][tid] + s_red[3][tid];
}

// ---------------- k_chunk: softmax + weighted sum + LayerNorm + partial max ----------------
// Block (b, g): 16 chunks; each wave handles 4 sequentially, tracks running
// max of its LN outputs; cross-wave LDS max -> pmax[b][g][768].
__global__ __launch_bounds__(256) void k_chunk(Args a) {
    __shared__ float s_max[4][D_];   // 12 KB
    const int tid = threadIdx.x, lane = tid & 63, wid = tid >> 6;
    const int b = blockIdx.x, g = blockIdx.y;
    const float LcV = *a.Lc;

    f32x4 rmax[3];
    #pragma unroll
    for (int p = 0; p < 3; ++p) rmax[p] = (f32x4)(-INFINITY);

    #pragma unroll 1
    for (int i = 0; i < 4; ++i) {
        int c = g * 16 + wid * 4 + i;
        int len = a.lens[b * C_ + c];
        len = max(0, min(len, LCK));
        int start = a.starts[b * C_ + c];
        float lg[LCK];
        #pragma unroll
        for (int l = 0; l < LCK; ++l) {
            bool valid = l < len;
            int t = valid ? (start + l) : start;   // start <= 381 < 512: in-bounds
            float v = a.partial[(size_t)b * S_ + t];
            lg[l] = valid ? v : LcV;
        }
        float m = lg[0];
        #pragma unroll
        for (int l = 1; l < LCK; ++l) m = fmaxf(m, lg[l]);
        float denom = 0.f;
        #pragma unroll
        for (int l = 0; l < LCK; ++l) { lg[l] = __expf(lg[l] - m); denom += lg[l]; }
        float inv = 1.0f / denom;

        const float* Xb = a.X + (size_t)b * S_ * D_;
        f32x4 o[3] = {(f32x4)(0.f), (f32x4)(0.f), (f32x4)(0.f)};
        for (int l = 0; l < len; ++l) {
            const float* row = Xb + (size_t)(start + l) * D_;
            float wgt = lg[l];
            #pragma unroll
            for (int p = 0; p < 3; ++p) {
                f32x4 xv = *(const f32x4*)(row + p * 256 + lane * 4);
                o[p] += xv * wgt;
            }
        }
        float sum = 0.f, sq = 0.f;
        #pragma unroll
        for (int p = 0; p < 3; ++p) {
            o[p] *= inv;
            #pragma unroll
            for (int j = 0; j < 4; ++j) { sum += o[p][j]; sq += o[p][j] * o[p][j]; }
        }
        #pragma unroll
        for (int off = 1; off < 64; off <<= 1) {
            sum += __shfl_xor(sum, off, 64);
            sq  += __shfl_xor(sq,  off, 64);
        }
        float u_   = sum * (1.0f / D_);
        float var  = fmaxf(sq * (1.0f / D_) - u_ * u_, 0.0f);
        float rstd = rsqrtf(var + 1e-12f);
        float* out = a.cf + ((size_t)b * C_ + c) * D_;
        #pragma unroll
        for (int p = 0; p < 3; ++p) {
            int d = p * 256 + lane * 4;
            f32x4 wv = *(const f32x4*)(a.lnw + d);
            f32x4 bv = *(const f32x4*)(a.lnb + d);
            f32x4 ov;
            #pragma unroll
            for (int j = 0; j < 4; ++j) {
                ov[j] = wv[j] * ((o[p][j] - u_) * rstd) + bv[j];
                rmax[p][j] = fmaxf(rmax[p][j], ov[j]);
            }
            *(f32x4*)(out + d) = ov;
        }
    }

    // cross-wave max -> pmax[b][g][:]
    #pragma unroll
    for (int p = 0; p < 3; ++p)
        *(f32x4*)&s_max[wid][p * 256 + lane * 4] = rmax[p];
    __syncthreads();
    if (wid == 0) {
        #pragma unroll
        for (int p = 0; p < 3; ++p) {
            int d = p * 256 + lane * 4;
            f32x4 m0 = *(const f32x4*)&s_max[0][d];
            f32x4 m1 = *(const f32x4*)&s_max[1][d];
            f32x4 m2 = *(const f32x4*)&s_max[2][d];
            f32x4 m3 = *(const f32x4*)&s_max[3][d];
            f32x4 mm;
            #pragma unroll
            for (int j = 0; j < 4; ++j)
                mm[j] = fmaxf(fmaxf(m0[j], m1[j]), fmaxf(m2[j], m3[j]));
            *(f32x4*)(a.pmax + ((size_t)b * 8 + g) * D_ + d) = mm;
        }
    }
}

// ---------------- k_maxlite: sent = max over the 8 partial maxima ----------------
__global__ __launch_bounds__(256) void k_maxlite(Args a) {
    int b = blockIdx.x;
    int d = blockIdx.y * 256 + threadIdx.x;
    const float* p = a.pmax + (size_t)b * 8 * D_ + d;
    float m = -INFINITY;
    #pragma unroll
    for (int g = 0; g < 8; ++g) m = fmaxf(m, p[(size_t)g * D_]);
    a.sent[(size_t)b * D_ + d] = m;
}

extern "C" void kernel_launch(void* const* d_in, const int* in_sizes, int n_in,
                              void* d_out, int out_size, void* d_ws, size_t ws_size,
                              hipStream_t stream) {
    Args a;
    a.X    = (const float*)d_in[0];   // (32,512,768)
    a.lens = (const int*)d_in[1];     // (32,128)
    a.W    = (const float*)d_in[2];   // (768,768)
    a.db   = (const float*)d_in[3];
    a.ab   = (const float*)d_in[4];
    a.q    = (const float*)d_in[5];
    a.lnw  = (const float*)d_in[6];
    a.lnb  = (const float*)d_in[7];

    a.cf   = (float*)d_out;                      // (32,128,768)
    a.sent = a.cf + (size_t)B_ * C_ * D_;        // (32,768)

    a.starts  = (int*)d_ws;                                       // 16 KB
    a.Tb      = (int*)((char*)d_ws + 16384);                      // 128 B
    a.Lc      = (float*)((char*)d_ws + 16640);                    // 4 B
    a.Wt      = (_Float16*)((char*)d_ws + 32768);                 // 1.125 MB
    a.partial = (float*)((char*)d_ws + 32768 + 1179648);          // 64 KB
    a.pmax    = (float*)((char*)d_ws + 32768 + 1179648 + 65536);  // 768 KB

    k_prep   <<<321,          256, 0, stream>>>(a);
    k_logits <<<P1_UNITS,     256, 0, stream>>>(a);
    k_chunk  <<<dim3(B_, 8),  256, 0, stream>>>(a);
    k_maxlite<<<dim3(B_, 3),  256, 0, stream>>>(a);
}

// Round 11
// 142.737 us; speedup vs baseline: 1.1310x; 1.1310x over previous
//
#include <hip/hip_runtime.h>
#include <math.h>

#define B_   32
#define S_   512
#define D_   768
#define C_   128   // MAX_CHUNK_NUMBER
#define LCK  8     // MAX_CHUNK_LEN

#define MT     32                 // rows per logits tile
#define NTILE  12                 // tiles per batch (Tb <= 381)
#define NKS    24                 // 32-wide k-steps
#define P1_UNITS (B_ * NTILE)     // 384 blocks: (b, tile); 8 waves each

typedef _Float16 half8_t __attribute__((ext_vector_type(8)));
typedef float    f32x4   __attribute__((ext_vector_type(4)));

struct Args {
    const float* X; const int* lens; const float* W;
    const float* db; const float* ab; const float* q;
    const float* lnw; const float* lnb;
    float* cf; float* sent;
    int* starts; int* Tb; float* Lc;
    _Float16* Wt;      // [48 etile][24 ks][64 lane][8] = 1.125 MB, frag-contiguous
    float* partial;    // [32 b][512 t]
    float* pmax;       // [32 b][8 g][768 d] partial maxima
};

__device__ __forceinline__ float fast_tanh(float x) {
    float e = __expf(2.0f * x);
    return 1.0f - 2.0f / (e + 1.0f);   // exact saturation at +/-inf
}

// ---------------- k_prep: Wt transpose | per-batch scan | Lc ----------------
// bid 0..287   : Wt[et][ks][lane][j] = (fp16) W[et*16+(lane&15)][ks*32+(lane>>4)*8+j]
// bid 288..319 : exclusive scan of chunk_lens for batch bid-288
// bid 320      : Lc = sum_e q[e]*tanh(db[e]+ab[e])
__global__ __launch_bounds__(256) void k_prep(Args a) {
    const int tid = threadIdx.x, bid = blockIdx.x;
    if (bid < 288) {
        int u    = bid * 256 + tid;        // 0..73727 frag-words
        int lane = u & 63;
        int ks   = (u >> 6) % NKS;
        int et   = u / (64 * NKS);
        int e    = et * 16 + (lane & 15);
        int k    = ks * 32 + ((lane >> 4) << 3);
        const float* src = a.W + (size_t)e * D_ + k;
        float4 f0 = *(const float4*)src;
        float4 f1 = *(const float4*)(src + 4);
        half8_t h;
        h[0] = (_Float16)f0.x; h[1] = (_Float16)f0.y;
        h[2] = (_Float16)f0.z; h[3] = (_Float16)f0.w;
        h[4] = (_Float16)f1.x; h[5] = (_Float16)f1.y;
        h[6] = (_Float16)f1.z; h[7] = (_Float16)f1.w;
        *(half8_t*)(a.Wt + (size_t)u * 8) = h;    // coalesced write
    } else if (bid < 320) {
        int b = bid - 288;
        __shared__ int s_scan[256];
        int v = (tid < C_) ? a.lens[b * C_ + tid] : 0;
        s_scan[tid] = v;
        __syncthreads();
        #pragma unroll
        for (int off = 1; off < C_; off <<= 1) {
            int add = (tid >= off) ? s_scan[tid - off] : 0;
            __syncthreads();
            s_scan[tid] += add;
            __syncthreads();
        }
        if (tid < C_) {
            a.starts[b * C_ + tid] = s_scan[tid] - v;
            if (tid == C_ - 1) a.Tb[b] = s_scan[C_ - 1];
        }
    } else {
        __shared__ float s_lcred[256];
        float p = 0.f;
        for (int e = tid; e < D_; e += 256) p += fast_tanh(a.db[e] + a.ab[e]) * a.q[e];
        s_lcred[tid] = p;
        __syncthreads();
        for (int off = 128; off > 0; off >>= 1) {
            if (tid < off) s_lcred[tid] += s_lcred[tid + off];
            __syncthreads();
        }
        if (tid == 0) *a.Lc = s_lcred[0];
    }
}

// ---------------- k_logits ----------------
// logit[b,t] = sum_e q[e]*tanh( sum_d X[b,t,d]*W[e,d] + db[e]+ab[e] )
// Block = (b, 32-row tile), 512 threads / 8 waves. X staged ONCE to 48 KB LDS
// (fp16, XOR-swizzled). Each wave: 6 e-tiles, per-ks chain = 6 coalesced 1-KB
// Wt loads (L2-resident) + 2 ds_read A-frags + 12 MFMA -> acc[2][6]
// (the r9-measured-fast per-wave schedule; 8 waves/block restores TLP).
// A-frag (16x16x32 f16): lane holds A[m0+mt*16+(l&15)][ks*32+(l>>4)*8+j]
// B-frag: lane holds W[e][same k], e = etile*16+(l&15), etile = wid*6+nt
// C/D: col=lane&15 (e), row=(lane>>4)*4+r (m)   [validated rounds 3-10]
__global__ __launch_bounds__(512) void k_logits(Args a) {
    __shared__ _Float16 Xs[MT * D_];   // 48 KB
    __shared__ float s_red[8][32];
    const int tid = threadIdx.x, lane = tid & 63, wid = tid >> 6;
    const int erow = lane & 15;
    const int krow = (lane >> 4) * 8;

    int u    = blockIdx.x;
    int b    = u / NTILE;
    int tile = u % NTILE;
    int m0   = tile * MT;
    if (m0 >= a.Tb[b]) return;   // block-uniform

    // ---- stage X tile (32 rows x 768 k) fp32 -> fp16 LDS, swizzled ----
    {
        const float* Xb = a.X + ((size_t)(b * S_ + m0)) * D_;
        #pragma unroll
        for (int it = 0; it < 6; ++it) {
            int idx = it * 512 + tid;        // 0..3071 half8 units
            int row = idx / 96;
            int kk8 = idx % 96;
            const float* src = Xb + (size_t)row * D_ + kk8 * 8;
            float4 f0 = *(const float4*)src;
            float4 f1 = *(const float4*)(src + 4);
            half8_t h;
            h[0] = (_Float16)f0.x; h[1] = (_Float16)f0.y;
            h[2] = (_Float16)f0.z; h[3] = (_Float16)f0.w;
            h[4] = (_Float16)f1.x; h[5] = (_Float16)f1.y;
            h[6] = (_Float16)f1.z; h[7] = (_Float16)f1.w;
            int byte = row * 1536 + kk8 * 16;
            byte ^= (row & 7) << 4;
            *(half8_t*)((char*)Xs + byte) = h;
        }
    }
    __syncthreads();

    // ---- K loop: 6 coalesced Wt frag loads + 12 MFMA per ks, per wave ----
    const int et0 = wid * 6;   // this wave: 6 e-tiles = 96 cols
    const _Float16* Wb = a.Wt + (((size_t)et0 * NKS) * 64 + lane) * 8;
    f32x4 acc[2][6];
    #pragma unroll
    for (int mt = 0; mt < 2; ++mt)
        #pragma unroll
        for (int nt = 0; nt < 6; ++nt) acc[mt][nt] = (f32x4)(0.f);

    #pragma unroll 4
    for (int ks = 0; ks < NKS; ++ks) {
        half8_t av[2];
        #pragma unroll
        for (int mt = 0; mt < 2; ++mt) {
            int row  = mt * 16 + erow;
            int byte = row * 1536 + (ks * 32 + krow) * 2;
            byte ^= (row & 7) << 4;
            av[mt] = *(const half8_t*)((const char*)Xs + byte);
        }
        #pragma unroll
        for (int nt = 0; nt < 6; ++nt) {
            half8_t bv = *(const half8_t*)(Wb + ((size_t)nt * NKS + ks) * 64 * 8);
            acc[0][nt] = __builtin_amdgcn_mfma_f32_16x16x32_f16(av[0], bv, acc[0][nt], 0, 0, 0);
            acc[1][nt] = __builtin_amdgcn_mfma_f32_16x16x32_f16(av[1], bv, acc[1][nt], 0, 0, 0);
        }
    }

    // ---- epilogue: tanh + q-dot ----
    float lsum[2][4] = {{0.f,0.f,0.f,0.f},{0.f,0.f,0.f,0.f}};
    #pragma unroll
    for (int nt = 0; nt < 6; ++nt) {
        int e = (et0 + nt) * 16 + erow;
        float beta = a.db[e] + a.ab[e];
        float qe = a.q[e];
        #pragma unroll
        for (int r = 0; r < 4; ++r) {
            lsum[0][r] += fast_tanh(acc[0][nt][r] + beta) * qe;
            lsum[1][r] += fast_tanh(acc[1][nt][r] + beta) * qe;
        }
    }
    #pragma unroll
    for (int off = 1; off < 16; off <<= 1)
        #pragma unroll
        for (int mt = 0; mt < 2; ++mt)
            #pragma unroll
            for (int r = 0; r < 4; ++r)
                lsum[mt][r] += __shfl_xor(lsum[mt][r], off, 64);

    __syncthreads();
    if (erow == 0) {
        #pragma unroll
        for (int mt = 0; mt < 2; ++mt)
            #pragma unroll
            for (int r = 0; r < 4; ++r)
                s_red[wid][mt * 16 + (lane >> 4) * 4 + r] = lsum[mt][r];
    }
    __syncthreads();
    if (tid < MT) {
        float s = 0.f;
        #pragma unroll
        for (int w = 0; w < 8; ++w) s += s_red[w][tid];
        a.partial[(size_t)b * S_ + m0 + tid] = s;
    }
}

// ---------------- k_chunk: softmax + weighted sum + LayerNorm + partial max ----------------
// Block (b, g): 16 chunks; each wave handles 4 sequentially, tracks running
// max of its LN outputs; cross-wave LDS max -> pmax[b][g][768].
__global__ __launch_bounds__(256) void k_chunk(Args a) {
    __shared__ float s_max[4][D_];   // 12 KB
    const int tid = threadIdx.x, lane = tid & 63, wid = tid >> 6;
    const int b = blockIdx.x, g = blockIdx.y;
    const float LcV = *a.Lc;

    f32x4 rmax[3];
    #pragma unroll
    for (int p = 0; p < 3; ++p) rmax[p] = (f32x4)(-INFINITY);

    #pragma unroll 1
    for (int i = 0; i < 4; ++i) {
        int c = g * 16 + wid * 4 + i;
        int len = a.lens[b * C_ + c];
        len = max(0, min(len, LCK));
        int start = a.starts[b * C_ + c];
        float lg[LCK];
        #pragma unroll
        for (int l = 0; l < LCK; ++l) {
            bool valid = l < len;
            int t = valid ? (start + l) : start;   // start <= 381 < 512: in-bounds
            float v = a.partial[(size_t)b * S_ + t];
            lg[l] = valid ? v : LcV;
        }
        float m = lg[0];
        #pragma unroll
        for (int l = 1; l < LCK; ++l) m = fmaxf(m, lg[l]);
        float denom = 0.f;
        #pragma unroll
        for (int l = 0; l < LCK; ++l) { lg[l] = __expf(lg[l] - m); denom += lg[l]; }
        float inv = 1.0f / denom;

        const float* Xb = a.X + (size_t)b * S_ * D_;
        f32x4 o[3] = {(f32x4)(0.f), (f32x4)(0.f), (f32x4)(0.f)};
        for (int l = 0; l < len; ++l) {
            const float* row = Xb + (size_t)(start + l) * D_;
            float wgt = lg[l];
            #pragma unroll
            for (int p = 0; p < 3; ++p) {
                f32x4 xv = *(const f32x4*)(row + p * 256 + lane * 4);
                o[p] += xv * wgt;
            }
        }
        float sum = 0.f, sq = 0.f;
        #pragma unroll
        for (int p = 0; p < 3; ++p) {
            o[p] *= inv;
            #pragma unroll
            for (int j = 0; j < 4; ++j) { sum += o[p][j]; sq += o[p][j] * o[p][j]; }
        }
        #pragma unroll
        for (int off = 1; off < 64; off <<= 1) {
            sum += __shfl_xor(sum, off, 64);
            sq  += __shfl_xor(sq,  off, 64);
        }
        float u_   = sum * (1.0f / D_);
        float var  = fmaxf(sq * (1.0f / D_) - u_ * u_, 0.0f);
        float rstd = rsqrtf(var + 1e-12f);
        float* out = a.cf + ((size_t)b * C_ + c) * D_;
        #pragma unroll
        for (int p = 0; p < 3; ++p) {
            int d = p * 256 + lane * 4;
            f32x4 wv = *(const f32x4*)(a.lnw + d);
            f32x4 bv = *(const f32x4*)(a.lnb + d);
            f32x4 ov;
            #pragma unroll
            for (int j = 0; j < 4; ++j) {
                ov[j] = wv[j] * ((o[p][j] - u_) * rstd) + bv[j];
                rmax[p][j] = fmaxf(rmax[p][j], ov[j]);
            }
            *(f32x4*)(out + d) = ov;
        }
    }

    // cross-wave max -> pmax[b][g][:]
    #pragma unroll
    for (int p = 0; p < 3; ++p)
        *(f32x4*)&s_max[wid][p * 256 + lane * 4] = rmax[p];
    __syncthreads();
    if (wid == 0) {
        #pragma unroll
        for (int p = 0; p < 3; ++p) {
            int d = p * 256 + lane * 4;
            f32x4 m0 = *(const f32x4*)&s_max[0][d];
            f32x4 m1 = *(const f32x4*)&s_max[1][d];
            f32x4 m2 = *(const f32x4*)&s_max[2][d];
            f32x4 m3 = *(const f32x4*)&s_max[3][d];
            f32x4 mm;
            #pragma unroll
            for (int j = 0; j < 4; ++j)
                mm[j] = fmaxf(fmaxf(m0[j], m1[j]), fmaxf(m2[j], m3[j]));
            *(f32x4*)(a.pmax + ((size_t)b * 8 + g) * D_ + d) = mm;
        }
    }
}

// ---------------- k_maxlite: sent = max over the 8 partial maxima ----------------
__global__ __launch_bounds__(256) void k_maxlite(Args a) {
    int b = blockIdx.x;
    int d = blockIdx.y * 256 + threadIdx.x;
    const float* p = a.pmax + (size_t)b * 8 * D_ + d;
    float m = -INFINITY;
    #pragma unroll
    for (int g = 0; g < 8; ++g) m = fmaxf(m, p[(size_t)g * D_]);
    a.sent[(size_t)b * D_ + d] = m;
}

extern "C" void kernel_launch(void* const* d_in, const int* in_sizes, int n_in,
                              void* d_out, int out_size, void* d_ws, size_t ws_size,
                              hipStream_t stream) {
    Args a;
    a.X    = (const float*)d_in[0];   // (32,512,768)
    a.lens = (const int*)d_in[1];     // (32,128)
    a.W    = (const float*)d_in[2];   // (768,768)
    a.db   = (const float*)d_in[3];
    a.ab   = (const float*)d_in[4];
    a.q    = (const float*)d_in[5];
    a.lnw  = (const float*)d_in[6];
    a.lnb  = (const float*)d_in[7];

    a.cf   = (float*)d_out;                      // (32,128,768)
    a.sent = a.cf + (size_t)B_ * C_ * D_;        // (32,768)

    a.starts  = (int*)d_ws;                                       // 16 KB
    a.Tb      = (int*)((char*)d_ws + 16384);                      // 128 B
    a.Lc      = (float*)((char*)d_ws + 16640);                    // 4 B
    a.Wt      = (_Float16*)((char*)d_ws + 32768);                 // 1.125 MB
    a.partial = (float*)((char*)d_ws + 32768 + 1179648);          // 64 KB
    a.pmax    = (float*)((char*)d_ws + 32768 + 1179648 + 65536);  // 768 KB

    k_prep   <<<321,          256, 0, stream>>>(a);
    k_logits <<<P1_UNITS,     512, 0, stream>>>(a);
    k_chunk  <<<dim3(B_, 8),  256, 0, stream>>>(a);
    k_maxlite<<<dim3(B_, 3),  256, 0, stream>>>(a);
}